// Round 5
// baseline (444.405 us; speedup 1.0000x reference)
//
#include <hip/hip_runtime.h>
#include <math.h>

// GaussianLayer: per row (B=524288): mu=x[0], sigma=exp(0.5*x[1]);
// pdf over xx=-99..99, cumsum over 199 bins. Output (B,199) fp32 = 417 MB.
//
// Accounting: dur_us = our kernel + ~270 us / 1.67 GB harness poison fill
// (Dispatch_Id pattern proves exactly 2 dispatches/iteration). Kernel-proper
// ~143-164 us across R6/R8/R9/R10 vs 67 us at the fill's 6.26 TB/s.
//
// Falsified: write-allocate fetch (R6), L2 bypass (R7 -> NaN, poison
// clobber), inter-block stalls (R8), LDS/barrier structure (R9),
// write-front density (R10). Four disjoint structures, same time.
//
// R11 theory: the fill keeps ~64 KB of writes in flight PER WAVE (63
// back-to-back stores, no dependent work). All our kernels interleave each
// store with 100-2000cy dependency chains and periodically issue a vmem
// load whose consumer wait drains ALL older stores (vmcnt is one in-order
// counter) -> time-averaged outstanding writes ~10-14 KB/CU vs the
// ~15-20 KB needed to cover HBM write latency -> ~half of peak.
// Fix = wave specialization: 3 producer waves/block compute 8-row slots
// into double-buffered LDS (scan via DPP on the VALU pipe, DS pipe kept
// free); 1 writer wave/block free-runs ds_read_b128 -> store_dwordx4 via
// LDS flags, no barriers, no drains -- structurally a fill wave. The fill
// saturates with ~3 such waves/CU; we have 4.

#define NT        256
#define NBLK      1024        // 4 blocks/CU (LDS-limited: 38.4 KB/block)
#define PRODUCERS 3
#define SLOT_ROWS 8           // B % 8 == 0 -> slots are always full or empty
#define TILE_ROWS 24          // PRODUCERS * SLOT_ROWS
#define ROWF      200         // padded floats/row in LDS (199+1) -> 16B-aligned rows
#define SLOT_F    (SLOT_ROWS * ROWF)   // 1600 floats = 6400 B
#define NB        199

typedef float fx4 __attribute__((ext_vector_type(4)));

__device__ __forceinline__ float bcast(float v, int lane) {
    return __int_as_float(__builtin_amdgcn_readlane(__float_as_int(v), lane));
}

// wave64 inclusive scan on the VALU pipe (LLVM AtomicOptimizer pattern):
// row_shr 1/2/4/8 within rows of 16, then row_bcast15 (rows 1,3),
// row_bcast31 (rows 2,3). old=0 -> shifted-in lanes contribute identity.
template<int CTRL, int RMASK>
__device__ __forceinline__ float dpp_add(float x) {
    int t = __builtin_amdgcn_update_dpp(0, __float_as_int(x), CTRL, RMASK, 0xF, false);
    return x + __int_as_float(t);
}
__device__ __forceinline__ float wave_iscan(float x) {
    x = dpp_add<0x111, 0xF>(x);   // row_shr:1
    x = dpp_add<0x112, 0xF>(x);   // row_shr:2
    x = dpp_add<0x114, 0xF>(x);   // row_shr:4
    x = dpp_add<0x118, 0xF>(x);   // row_shr:8
    x = dpp_add<0x142, 0xA>(x);   // row_bcast:15 -> rows 1,3
    x = dpp_add<0x143, 0xC>(x);   // row_bcast:31 -> rows 2,3
    return x;
}

__global__ __launch_bounds__(NT, 4)
void gauss_cdf_kernel(const float2* __restrict__ x, float* __restrict__ out, int B) {
    __shared__ __align__(16) float slots[PRODUCERS][2][SLOT_F];   // 38,400 B
    __shared__ int flags[PRODUCERS][2];                           // 0=free, 1=full

    const int tid = threadIdx.x;
    const int l   = tid & 63;
    const int wid = tid >> 6;            // 0..2 producers, 3 writer

    if (tid < PRODUCERS * 2) ((volatile int*)flags)[tid] = 0;
    __syncthreads();                     // once, before the pipeline starts

    const int nTiles = (B + TILE_ROWS - 1) / TILE_ROWS;

    if (wid < PRODUCERS) {
        // ---------------- producer wave ----------------
        const int   p    = wid;
        const float bl   = 4.0f * (float)l - 99.0f;
        const bool  full = (l <= 48);
        const bool  any  = (l <= 49);
        int parity = 0;
        for (int tile = blockIdx.x; tile < nTiles; tile += NBLK, parity ^= 1) {
            const int rowBase = tile * TILE_ROWS + p * SLOT_ROWS;
            if (rowBase >= B) continue;          // empty slot: no flag traffic
            const int rmax = (B - rowBase < SLOT_ROWS) ? (B - rowBase) : SLOT_ROWS;

            // issue this slot's param load BEFORE the poll (poll hides latency);
            // producers issue NO stores, so this wait can't drain write traffic.
            float2 vx = x[rowBase + (l & 7) < B ? rowBase + (l & 7) : B - 1];

            volatile int* f = &flags[p][parity];
            while (*f != 0) __builtin_amdgcn_s_sleep(2);

            float* slot = (float*)slots[p][parity];
            #pragma unroll
            for (int r = 0; r < SLOT_ROWS; ++r) {
                if (r >= rmax) break;            // rmax==8 for B=524288
                const float mu   = bcast(vx.x, r);
                const float lsig = bcast(vx.y, r);
                // -log2e/2 = -0.72134752; log2(1/sqrt(2pi)) = -1.32574806
                const float li = -1.3257480647361593f - 0.7213475204444817f * lsig;
                const float s  = __builtin_amdgcn_exp2f(-0.7213475204444817f * lsig);
                const float ca = -0.7213475204444817f * s * s;   // -log2e/(2 s^2)
                const float t0 = bl - mu, t1 = t0 + 1.f, t2 = t0 + 2.f, t3 = t0 + 3.f;
                float p0 = __builtin_amdgcn_exp2f(__builtin_fmaf(ca, t0 * t0, li));
                float p1 = __builtin_amdgcn_exp2f(__builtin_fmaf(ca, t1 * t1, li));
                float p2 = __builtin_amdgcn_exp2f(__builtin_fmaf(ca, t2 * t2, li));
                float p3 = __builtin_amdgcn_exp2f(__builtin_fmaf(ca, t3 * t3, li));
                if (!any)  { p0 = 0.f; p1 = 0.f; p2 = 0.f; }   // lanes 50..63
                if (!full) { p3 = 0.f; }                        // lane 49: no bin 199
                const float c0 = p0, c1 = c0 + p1, c2 = c1 + p2, c3 = c2 + p3;
                const float sc = wave_iscan(c3);                // VALU-pipe scan
                const float e  = sc - c3;
                fx4 o; o.x = e + c0; o.y = e + c1; o.z = e + c2; o.w = e + c3;
                if (any) *(fx4*)(slot + r * ROWF + 4 * l) = o;  // 16B-aligned
            }
            asm volatile("s_waitcnt lgkmcnt(0)" ::: "memory");  // data visible first
            __builtin_amdgcn_sched_barrier(0);
            if (l == 0) *(volatile int*)&flags[p][parity] = 1;
        }
    } else {
        // ---------------- writer wave (fill-style) ----------------
        const bool full = (l <= 48);
        const bool any  = (l <= 49);
        int parity = 0;
        for (int tile = blockIdx.x; tile < nTiles; tile += NBLK, parity ^= 1) {
            #pragma unroll
            for (int p = 0; p < PRODUCERS; ++p) {
                const int rowBase = tile * TILE_ROWS + p * SLOT_ROWS;
                if (rowBase >= B) continue;
                const int rmax = (B - rowBase < SLOT_ROWS) ? (B - rowBase) : SLOT_ROWS;

                volatile int* f = &flags[p][parity];
                while (*f != 1) __builtin_amdgcn_s_sleep(2);

                const float* slot = (const float*)slots[p][parity];
                fx4 v[SLOT_ROWS];
                #pragma unroll
                for (int r = 0; r < SLOT_ROWS; ++r)
                    if (r < rmax && any) v[r] = *(const fx4*)(slot + r * ROWF + 4 * l);
                asm volatile("s_waitcnt lgkmcnt(0)" ::: "memory");  // reads landed
                __builtin_amdgcn_sched_barrier(0);
                if (l == 0) *f = 0;      // free slot now: store data is in regs

                #pragma unroll
                for (int r = 0; r < SLOT_ROWS; ++r) {
                    if (r >= rmax) break;
                    float* ro = out + (size_t)(rowBase + r) * NB;
                    if (full) {
                        __builtin_memcpy(ro + 4 * l, &v[r], 16);   // 4B-aligned ok
                    } else if (l == 49) {
                        __builtin_memcpy(ro + 196, &v[r], 12);     // bins 196..198
                    }
                }
                // no vmcnt drain: compiler paces register reuse with counted waits
            }
        }
    }
}

extern "C" void kernel_launch(void* const* d_in, const int* in_sizes, int n_in,
                              void* d_out, int out_size, void* d_ws, size_t ws_size,
                              hipStream_t stream) {
    const float2* x = (const float2*)d_in[0];
    float* out = (float*)d_out;
    const int B = in_sizes[0] / 2;                  // (B,2) fp32
    gauss_cdf_kernel<<<NBLK, NT, 0, stream>>>(x, out, B);
}